// Round 1
// baseline (1122.531 us; speedup 1.0000x reference)
//
#include <hip/hip_runtime.h>

#define U_NUMC 100000
#define I_NUMC 50000
#define NNODES 150000
#define EMB 64
#define NBATCH 8192

// ---------------- init: concat(uEmbd, iEmbd) -> f0 and acc ----------------
__global__ __launch_bounds__(256) void k_init(const float* __restrict__ uE,
                                              const float* __restrict__ iE,
                                              float* __restrict__ f0,
                                              float* __restrict__ acc) {
    const int total = NNODES * EMB / 4;      // float4 elements
    const int uCount = U_NUMC * EMB / 4;
    const float4* u4 = (const float4*)uE;
    const float4* i4 = (const float4*)iE;
    for (int idx = blockIdx.x * blockDim.x + threadIdx.x; idx < total;
         idx += gridDim.x * blockDim.x) {
        float4 v = (idx < uCount) ? u4[idx] : i4[idx - uCount];
        ((float4*)f0)[idx] = v;
        ((float4*)acc)[idx] = v;
    }
}

// ---------------- zero small int buffer ----------------
__global__ __launch_bounds__(256) void k_zero(int* __restrict__ p, int n) {
    int i = blockIdx.x * blockDim.x + threadIdx.x;
    if (i < n) p[i] = 0;
}

// ---------------- user row_ptr via binary search (rows1 sorted) ----------------
__global__ __launch_bounds__(256) void k_uptr(const int* __restrict__ rows1, int E1,
                                              int* __restrict__ uptr) {
    int r = blockIdx.x * blockDim.x + threadIdx.x;
    if (r > U_NUMC) return;
    int lo = 0, hi = E1;                     // first e with rows1[e] >= r
    while (lo < hi) {
        int mid = (lo + hi) >> 1;
        if (rows1[mid] < r) lo = mid + 1; else hi = mid;
    }
    uptr[r] = lo;
}

// ---------------- histogram of items from first-half cols (= i + U_NUM) -------
__global__ __launch_bounds__(256) void k_hist(const int* __restrict__ cols1, int E1,
                                              int* __restrict__ hist) {
    int e = blockIdx.x * blockDim.x + threadIdx.x;
    if (e >= E1) return;
    atomicAdd(&hist[cols1[e] - U_NUMC], 1);
}

// ---------------- single-block exclusive scan hist -> iptr (+cursor copy) -----
__global__ __launch_bounds__(1024) void k_scan(const int* __restrict__ hist,
                                               int* __restrict__ iptr,
                                               int* __restrict__ cursor) {
    __shared__ int lds[1024];
    int carry = 0;
    const int tid = threadIdx.x;
    for (int base = 0; base < I_NUMC; base += 1024) {
        int idx = base + tid;
        int v = (idx < I_NUMC) ? hist[idx] : 0;
        int x = v;
        for (int offd = 1; offd < 1024; offd <<= 1) {
            lds[tid] = x;
            __syncthreads();
            int y = (tid >= offd) ? lds[tid - offd] : 0;
            __syncthreads();
            x += y;
        }
        if (idx < I_NUMC) {
            int excl = carry + x - v;
            iptr[idx] = excl;
            cursor[idx] = excl;
        }
        lds[tid] = x;
        __syncthreads();
        carry += lds[1023];
        __syncthreads();
    }
    if (tid == 0) iptr[I_NUMC] = carry;
}

// ---------------- scatter first-half edges into item-CSR order ----------------
__global__ __launch_bounds__(256) void k_scatter(const int* __restrict__ rows1,
                                                 const int* __restrict__ cols1,
                                                 const float* __restrict__ vals1,
                                                 int E1,
                                                 int* __restrict__ cursor,
                                                 int* __restrict__ item_u,
                                                 float* __restrict__ item_v) {
    int e = blockIdx.x * blockDim.x + threadIdx.x;
    if (e >= E1) return;
    int i = cols1[e] - U_NUMC;
    int pos = atomicAdd(&cursor[i], 1);
    item_u[pos] = rows1[e];                  // user node index (direct f row)
    item_v[pos] = vals1[e];
}

// ---------------- SpMM: one wave per output row, lane = dim -------------------
__global__ __launch_bounds__(256) void k_spmm(const float* __restrict__ f,
                                              float* __restrict__ fn,
                                              float* __restrict__ acc,
                                              const int* __restrict__ uptr,
                                              const int* __restrict__ cols1,
                                              const float* __restrict__ vals1,
                                              const int* __restrict__ iptr,
                                              const int* __restrict__ item_u,
                                              const float* __restrict__ item_v) {
    int wave = (blockIdx.x * blockDim.x + threadIdx.x) >> 6;
    int lane = threadIdx.x & 63;
    if (wave >= NNODES) return;

    int beg, end;
    const int* ci;
    const float* vi;
    if (wave < U_NUMC) {
        beg = uptr[wave]; end = uptr[wave + 1];
        ci = cols1; vi = vals1;              // cols1[e] is a global node index
    } else {
        int i = wave - U_NUMC;
        beg = iptr[i]; end = iptr[i + 1];
        ci = item_u; vi = item_v;            // item_u[e] is a global node index
    }

    float sum = 0.f;
    for (int base = beg; base < end; base += 64) {
        int c = 0; float v = 0.f;
        if (base + lane < end) { c = ci[base + lane]; v = vi[base + lane]; }
        int n = min(64, end - base);
        for (int j = 0; j < n; ++j) {
            int   cj = __shfl(c, j);
            float vj = __shfl(v, j);
            sum += vj * f[cj * EMB + lane];  // 256B coalesced gather
        }
    }
    int o = wave * EMB + lane;
    fn[o] = sum;
    acc[o] += sum;
}

// ---------------- batched dot of final embeddings ----------------
__global__ __launch_bounds__(256) void k_out(const float* __restrict__ acc,
                                             const int* __restrict__ userIdx,
                                             const int* __restrict__ itemIdx,
                                             float* __restrict__ out) {
    int wave = (blockIdx.x * blockDim.x + threadIdx.x) >> 6;
    int lane = threadIdx.x & 63;
    if (wave >= NBATCH) return;
    int u = userIdx[wave];
    int it = itemIdx[wave] + U_NUMC;
    float p = acc[u * EMB + lane] * acc[it * EMB + lane];
    #pragma unroll
    for (int offd = 32; offd; offd >>= 1) p += __shfl_xor(p, offd);
    if (lane == 0) out[wave] = p * (1.0f / 16.0f);   // (acc/4)·(acc/4)
}

extern "C" void kernel_launch(void* const* d_in, const int* in_sizes, int n_in,
                              void* d_out, int out_size, void* d_ws, size_t ws_size,
                              hipStream_t stream) {
    const float* uE      = (const float*)d_in[0];
    const float* iE      = (const float*)d_in[1];
    const int*   rows    = (const int*)d_in[2];    // [E], first half sorted by u
    const int*   cols    = (const int*)d_in[3];    // [E], first half = i + U_NUM
    const float* vals    = (const float*)d_in[4];  // [E], symmetric halves
    const int*   userIdx = (const int*)d_in[5];
    const int*   itemIdx = (const int*)d_in[6];
    const int E  = in_sizes[2];
    const int E1 = E / 2;

    char* ws = (char*)d_ws;
    size_t off = 0;
    auto alloc = [&](size_t bytes) -> void* {
        off = (off + 255) & ~(size_t)255;
        void* p = ws + off;
        off += bytes;
        return p;
    };
    float* f0     = (float*)alloc((size_t)NNODES * EMB * 4);
    float* f1     = (float*)alloc((size_t)NNODES * EMB * 4);
    float* acc    = (float*)alloc((size_t)NNODES * EMB * 4);
    int*   uptr   = (int*)alloc((size_t)(U_NUMC + 1) * 4);
    int*   iptr   = (int*)alloc((size_t)(I_NUMC + 1) * 4);
    int*   hist   = (int*)alloc((size_t)I_NUMC * 4);
    int*   cursor = (int*)alloc((size_t)I_NUMC * 4);
    int*   item_u = (int*)alloc((size_t)E1 * 4);
    float* item_v = (float*)alloc((size_t)E1 * 4);

    // init feats + acc; zero histogram
    k_init<<<2048, 256, 0, stream>>>(uE, iE, f0, acc);
    k_zero<<<(I_NUMC + 255) / 256, 256, 0, stream>>>(hist, I_NUMC);

    // index structures (built every call; amortized over 3 SpMM layers)
    k_uptr<<<(U_NUMC + 256) / 256, 256, 0, stream>>>(rows, E1, uptr);
    k_hist<<<(E1 + 255) / 256, 256, 0, stream>>>(cols, E1, hist);
    k_scan<<<1, 1024, 0, stream>>>(hist, iptr, cursor);
    k_scatter<<<(E1 + 255) / 256, 256, 0, stream>>>(rows, cols, vals, E1,
                                                    cursor, item_u, item_v);

    // 3 propagation layers, f alternates f0 <-> f1, acc accumulates
    const int spmm_blocks = NNODES / 4;      // 4 waves (rows) per 256-thr block
    const float* fc = f0;
    float* fn = f1;
    for (int l = 0; l < 3; ++l) {
        k_spmm<<<spmm_blocks, 256, 0, stream>>>(fc, fn, acc,
                                                uptr, cols, vals,
                                                iptr, item_u, item_v);
        float* t = (float*)fc; fc = fn; fn = t;
    }

    // final batched dot products
    k_out<<<NBATCH / 4, 256, 0, stream>>>(acc, userIdx, itemIdx, (float*)d_out);
}

// Round 2
// 763.900 us; speedup vs baseline: 1.4695x; 1.4695x over previous
//
#include <hip/hip_runtime.h>

#define U_NUMC 100000
#define I_NUMC 50000
#define NNODES 150000
#define EMB 64
#define NBATCH 8192
#define NB_I ((I_NUMC + 255) / 256)   // 196 blocks over item histogram

// ---------------- init: concat(uEmbd, iEmbd) -> f0 and acc ----------------
__global__ __launch_bounds__(256) void k_init(const float* __restrict__ uE,
                                              const float* __restrict__ iE,
                                              float* __restrict__ f0,
                                              float* __restrict__ acc) {
    const int total = NNODES * EMB / 4;      // float4 elements
    const int uCount = U_NUMC * EMB / 4;
    const float4* u4 = (const float4*)uE;
    const float4* i4 = (const float4*)iE;
    for (int idx = blockIdx.x * blockDim.x + threadIdx.x; idx < total;
         idx += gridDim.x * blockDim.x) {
        float4 v = (idx < uCount) ? u4[idx] : i4[idx - uCount];
        ((float4*)f0)[idx] = v;
        ((float4*)acc)[idx] = v;
    }
}

// ---------------- zero small int buffer ----------------
__global__ __launch_bounds__(256) void k_zero(int* __restrict__ p, int n) {
    int i = blockIdx.x * blockDim.x + threadIdx.x;
    if (i < n) p[i] = 0;
}

// ---------------- user row_ptr via binary search (rows1 sorted) ----------------
__global__ __launch_bounds__(256) void k_uptr(const int* __restrict__ rows1, int E1,
                                              int* __restrict__ uptr) {
    int r = blockIdx.x * blockDim.x + threadIdx.x;
    if (r > U_NUMC) return;
    int lo = 0, hi = E1;                     // first e with rows1[e] >= r
    while (lo < hi) {
        int mid = (lo + hi) >> 1;
        if (rows1[mid] < r) lo = mid + 1; else hi = mid;
    }
    uptr[r] = lo;
}

// ---------------- histogram of items from first-half cols (= i + U_NUM) -------
__global__ __launch_bounds__(256) void k_hist(const int* __restrict__ cols1, int E1,
                                              int* __restrict__ hist) {
    int e = blockIdx.x * blockDim.x + threadIdx.x;
    if (e >= E1) return;
    atomicAdd(&hist[cols1[e] - U_NUMC], 1);
}

// ---------------- hierarchical scan: (1) per-block sums ----------------
__global__ __launch_bounds__(256) void k_scan1(const int* __restrict__ hist,
                                               int* __restrict__ bsum) {
    int b = blockIdx.x, t = threadIdx.x;
    int idx = b * 256 + t;
    int v = (idx < I_NUMC) ? hist[idx] : 0;
    #pragma unroll
    for (int o = 32; o; o >>= 1) v += __shfl_xor(v, o);
    __shared__ int ws4[4];
    if ((t & 63) == 0) ws4[t >> 6] = v;
    __syncthreads();
    if (t == 0) bsum[b] = ws4[0] + ws4[1] + ws4[2] + ws4[3];
}

// ---------------- (2) scan the 196 block sums (single block) ----------------
__global__ __launch_bounds__(256) void k_scan2(const int* __restrict__ bsum,
                                               int* __restrict__ boff,
                                               int* __restrict__ iptr) {
    __shared__ int lds[256];
    int t = threadIdx.x;
    int v = (t < NB_I) ? bsum[t] : 0;
    int x = v;
    #pragma unroll
    for (int o = 1; o < 256; o <<= 1) {
        lds[t] = x; __syncthreads();
        int y = (t >= o) ? lds[t - o] : 0; __syncthreads();
        x += y;
    }
    if (t < NB_I) boff[t] = x - v;           // exclusive block offset
    if (t == 255) iptr[I_NUMC] = x;          // grand total
}

// ---------------- (3) per-block rescan + write iptr & cursor ----------------
__global__ __launch_bounds__(256) void k_scan3(const int* __restrict__ hist,
                                               const int* __restrict__ boff,
                                               int* __restrict__ iptr,
                                               int* __restrict__ cursor) {
    __shared__ int lds[256];
    int b = blockIdx.x, t = threadIdx.x;
    int idx = b * 256 + t;
    int v = (idx < I_NUMC) ? hist[idx] : 0;
    int x = v;
    #pragma unroll
    for (int o = 1; o < 256; o <<= 1) {
        lds[t] = x; __syncthreads();
        int y = (t >= o) ? lds[t - o] : 0; __syncthreads();
        x += y;
    }
    if (idx < I_NUMC) {
        int excl = boff[b] + x - v;
        iptr[idx] = excl;
        cursor[idx] = excl;
    }
}

// ---------------- scatter first-half edges into item-CSR order ----------------
__global__ __launch_bounds__(256) void k_scatter(const int* __restrict__ rows1,
                                                 const int* __restrict__ cols1,
                                                 const float* __restrict__ vals1,
                                                 int E1,
                                                 int* __restrict__ cursor,
                                                 int* __restrict__ item_u,
                                                 float* __restrict__ item_v) {
    int e = blockIdx.x * blockDim.x + threadIdx.x;
    if (e >= E1) return;
    int i = cols1[e] - U_NUMC;
    int pos = atomicAdd(&cursor[i], 1);
    item_u[pos] = rows1[e];                  // user node index (direct f row)
    item_v[pos] = vals1[e];
}

// ---------------- SpMM: one wave per output row, lane = dim -------------------
// 8-deep gather pipeline: all lanes hold a clamped edge (v=0 past end), so
// every group of 8 broadcast slots is valid; out-of-range slots gather the
// last row again (L2-hot) with weight 0.
__global__ __launch_bounds__(256) void k_spmm(const float* __restrict__ f,
                                              float* __restrict__ fn,
                                              float* __restrict__ acc,
                                              const int* __restrict__ uptr,
                                              const int* __restrict__ cols1,
                                              const float* __restrict__ vals1,
                                              const int* __restrict__ iptr,
                                              const int* __restrict__ item_u,
                                              const float* __restrict__ item_v) {
    int wave = (blockIdx.x * blockDim.x + threadIdx.x) >> 6;
    int lane = threadIdx.x & 63;
    if (wave >= NNODES) return;

    int beg, end;
    const int* ci;
    const float* vi;
    if (wave < U_NUMC) {
        beg = uptr[wave]; end = uptr[wave + 1];
        ci = cols1; vi = vals1;              // cols1[e] is a global node index
    } else {
        int i = wave - U_NUMC;
        beg = iptr[i]; end = iptr[i + 1];
        ci = item_u; vi = item_v;            // item_u[e] is a global node index
    }

    float sum = 0.f;
    for (int base = beg; base < end; base += 64) {
        int idx = base + lane;
        int ld = min(idx, end - 1);
        int c = ci[ld];
        float v = (idx < end) ? vi[ld] : 0.f;
        int n = min(64, end - base);
        for (int j = 0; j < n; j += 8) {
            float l[8], vv[8];
            #pragma unroll
            for (int t = 0; t < 8; ++t) {
                int cj = __shfl(c, j + t);
                vv[t] = __shfl(v, j + t);
                l[t] = f[cj * EMB + lane];   // 8 independent 256B gathers
            }
            #pragma unroll
            for (int t = 0; t < 8; ++t) sum += vv[t] * l[t];
        }
    }
    int o = wave * EMB + lane;
    fn[o] = sum;
    acc[o] += sum;
}

// ---------------- batched dot of final embeddings ----------------
__global__ __launch_bounds__(256) void k_out(const float* __restrict__ acc,
                                             const int* __restrict__ userIdx,
                                             const int* __restrict__ itemIdx,
                                             float* __restrict__ out) {
    int wave = (blockIdx.x * blockDim.x + threadIdx.x) >> 6;
    int lane = threadIdx.x & 63;
    if (wave >= NBATCH) return;
    int u = userIdx[wave];
    int it = itemIdx[wave] + U_NUMC;
    float p = acc[u * EMB + lane] * acc[it * EMB + lane];
    #pragma unroll
    for (int offd = 32; offd; offd >>= 1) p += __shfl_xor(p, offd);
    if (lane == 0) out[wave] = p * (1.0f / 16.0f);   // (acc/4)·(acc/4)
}

extern "C" void kernel_launch(void* const* d_in, const int* in_sizes, int n_in,
                              void* d_out, int out_size, void* d_ws, size_t ws_size,
                              hipStream_t stream) {
    const float* uE      = (const float*)d_in[0];
    const float* iE      = (const float*)d_in[1];
    const int*   rows    = (const int*)d_in[2];    // [E], first half sorted by u
    const int*   cols    = (const int*)d_in[3];    // [E], first half = i + U_NUM
    const float* vals    = (const float*)d_in[4];  // [E], symmetric halves
    const int*   userIdx = (const int*)d_in[5];
    const int*   itemIdx = (const int*)d_in[6];
    const int E  = in_sizes[2];
    const int E1 = E / 2;

    char* ws = (char*)d_ws;
    size_t off = 0;
    auto alloc = [&](size_t bytes) -> void* {
        off = (off + 255) & ~(size_t)255;
        void* p = ws + off;
        off += bytes;
        return p;
    };
    float* f0     = (float*)alloc((size_t)NNODES * EMB * 4);
    float* f1     = (float*)alloc((size_t)NNODES * EMB * 4);
    float* acc    = (float*)alloc((size_t)NNODES * EMB * 4);
    int*   uptr   = (int*)alloc((size_t)(U_NUMC + 1) * 4);
    int*   iptr   = (int*)alloc((size_t)(I_NUMC + 1) * 4);
    int*   hist   = (int*)alloc((size_t)I_NUMC * 4);
    int*   cursor = (int*)alloc((size_t)I_NUMC * 4);
    int*   bsum   = (int*)alloc((size_t)NB_I * 4);
    int*   boff   = (int*)alloc((size_t)NB_I * 4);
    int*   item_u = (int*)alloc((size_t)E1 * 4);
    float* item_v = (float*)alloc((size_t)E1 * 4);

    // init feats + acc; zero histogram
    k_init<<<2048, 256, 0, stream>>>(uE, iE, f0, acc);
    k_zero<<<(I_NUMC + 255) / 256, 256, 0, stream>>>(hist, I_NUMC);

    // index structures (built every call; amortized over 3 SpMM layers)
    k_uptr<<<(U_NUMC + 256) / 256, 256, 0, stream>>>(rows, E1, uptr);
    k_hist<<<(E1 + 255) / 256, 256, 0, stream>>>(cols, E1, hist);
    k_scan1<<<NB_I, 256, 0, stream>>>(hist, bsum);
    k_scan2<<<1, 256, 0, stream>>>(bsum, boff, iptr);
    k_scan3<<<NB_I, 256, 0, stream>>>(hist, boff, iptr, cursor);
    k_scatter<<<(E1 + 255) / 256, 256, 0, stream>>>(rows, cols, vals, E1,
                                                    cursor, item_u, item_v);

    // 3 propagation layers, f alternates f0 <-> f1, acc accumulates
    const int spmm_blocks = NNODES / 4;      // 4 waves (rows) per 256-thr block
    const float* fc = f0;
    float* fn = f1;
    for (int l = 0; l < 3; ++l) {
        k_spmm<<<spmm_blocks, 256, 0, stream>>>(fc, fn, acc,
                                                uptr, cols, vals,
                                                iptr, item_u, item_v);
        float* t = (float*)fc; fc = fn; fn = t;
    }

    // final batched dot products
    k_out<<<NBATCH / 4, 256, 0, stream>>>(acc, userIdx, itemIdx, (float*)d_out);
}

// Round 3
// 734.950 us; speedup vs baseline: 1.5274x; 1.0394x over previous
//
#include <hip/hip_runtime.h>

#define U_NUMC 100000
#define I_NUMC 50000
#define NNODES 150000
#define EMB 64
#define NBATCH 8192
#define NB_I ((I_NUMC + 255) / 256)   // 196 blocks over item histogram

// ---------------- zero small int buffer ----------------
__global__ __launch_bounds__(256) void k_zero(int* __restrict__ p, int n) {
    int i = blockIdx.x * blockDim.x + threadIdx.x;
    if (i < n) p[i] = 0;
}

// ---------------- user row_ptr via binary search (rows1 sorted) ----------------
__global__ __launch_bounds__(256) void k_uptr(const int* __restrict__ rows1, int E1,
                                              int* __restrict__ uptr) {
    int r = blockIdx.x * blockDim.x + threadIdx.x;
    if (r > U_NUMC) return;
    int lo = 0, hi = E1;                     // first e with rows1[e] >= r
    while (lo < hi) {
        int mid = (lo + hi) >> 1;
        if (rows1[mid] < r) lo = mid + 1; else hi = mid;
    }
    uptr[r] = lo;
}

// ---------------- histogram of items from first-half cols (= i + U_NUM) -------
__global__ __launch_bounds__(256) void k_hist(const int* __restrict__ cols1, int E1,
                                              int* __restrict__ hist) {
    int e = blockIdx.x * blockDim.x + threadIdx.x;
    if (e >= E1) return;
    atomicAdd(&hist[cols1[e] - U_NUMC], 1);
}

// ---------------- hierarchical scan: (1) per-block sums ----------------
__global__ __launch_bounds__(256) void k_scan1(const int* __restrict__ hist,
                                               int* __restrict__ bsum) {
    int b = blockIdx.x, t = threadIdx.x;
    int idx = b * 256 + t;
    int v = (idx < I_NUMC) ? hist[idx] : 0;
    #pragma unroll
    for (int o = 32; o; o >>= 1) v += __shfl_xor(v, o);
    __shared__ int ws4[4];
    if ((t & 63) == 0) ws4[t >> 6] = v;
    __syncthreads();
    if (t == 0) bsum[b] = ws4[0] + ws4[1] + ws4[2] + ws4[3];
}

// ---------------- (2) scan the 196 block sums (single block) ----------------
__global__ __launch_bounds__(256) void k_scan2(const int* __restrict__ bsum,
                                               int* __restrict__ boff,
                                               int* __restrict__ iptr) {
    __shared__ int lds[256];
    int t = threadIdx.x;
    int v = (t < NB_I) ? bsum[t] : 0;
    int x = v;
    #pragma unroll
    for (int o = 1; o < 256; o <<= 1) {
        lds[t] = x; __syncthreads();
        int y = (t >= o) ? lds[t - o] : 0; __syncthreads();
        x += y;
    }
    if (t < NB_I) boff[t] = x - v;           // exclusive block offset
    if (t == 255) iptr[I_NUMC] = x;          // grand total
}

// ---------------- (3) per-block rescan + write iptr & cursor ----------------
__global__ __launch_bounds__(256) void k_scan3(const int* __restrict__ hist,
                                               const int* __restrict__ boff,
                                               int* __restrict__ iptr,
                                               int* __restrict__ cursor) {
    __shared__ int lds[256];
    int b = blockIdx.x, t = threadIdx.x;
    int idx = b * 256 + t;
    int v = (idx < I_NUMC) ? hist[idx] : 0;
    int x = v;
    #pragma unroll
    for (int o = 1; o < 256; o <<= 1) {
        lds[t] = x; __syncthreads();
        int y = (t >= o) ? lds[t - o] : 0; __syncthreads();
        x += y;
    }
    if (idx < I_NUMC) {
        int excl = boff[b] + x - v;
        iptr[idx] = excl;
        cursor[idx] = excl;
    }
}

// ------- scatter first-half edges into item-CSR order, packed (u, val) -------
__global__ __launch_bounds__(256) void k_scatter(const int* __restrict__ rows1,
                                                 const int* __restrict__ cols1,
                                                 const float* __restrict__ vals1,
                                                 int E1,
                                                 int* __restrict__ cursor,
                                                 int2* __restrict__ item_uv) {
    int e = blockIdx.x * blockDim.x + threadIdx.x;
    if (e >= E1) return;
    int i = cols1[e] - U_NUMC;
    int pos = atomicAdd(&cursor[i], 1);
    item_uv[pos] = make_int2(rows1[e], __float_as_int(vals1[e]));
}

// ---------------- SpMM: one wave per output row, lane = dim -------------------
// 8-deep gather pipeline: all lanes hold a clamped edge (v=0 past end), so
// every group of 8 broadcast slots is valid; out-of-range slots gather the
// last row again (L2-hot) with weight 0.
// FIRST: gather from split uE/iE (base is wave-uniform: bipartite halves),
//        and initialize acc = own_feat + sum.
// LAST:  skip the fn store (only acc is consumed afterwards).
template <int FIRST, int LAST>
__global__ __launch_bounds__(256) void k_spmm(const float* __restrict__ uE,
                                              const float* __restrict__ iE,
                                              const float* __restrict__ f,
                                              float* __restrict__ fn,
                                              float* __restrict__ acc,
                                              const int* __restrict__ uptr,
                                              const int* __restrict__ cols1,
                                              const float* __restrict__ vals1,
                                              const int* __restrict__ iptr,
                                              const int2* __restrict__ item_uv) {
    int wave = (blockIdx.x * blockDim.x + threadIdx.x) >> 6;
    int lane = threadIdx.x & 63;
    if (wave >= NNODES) return;

    const bool isUser = (wave < U_NUMC);
    int beg, end;
    if (isUser) { beg = uptr[wave];           end = uptr[wave + 1]; }
    else        { int i = wave - U_NUMC; beg = iptr[i]; end = iptr[i + 1]; }

    // Gather base: user rows gather item nodes, item rows gather user nodes.
    const float* fb;
    if (FIRST) fb = isUser ? (iE - (size_t)U_NUMC * EMB) : uE;
    else       fb = f;

    float sum = 0.f;
    for (int base = beg; base < end; base += 64) {
        int idx = base + lane;
        int ld = min(idx, end - 1);
        int c; float v;
        if (isUser) {
            c = cols1[ld];
            v = (idx < end) ? vals1[ld] : 0.f;
        } else {
            int2 e = item_uv[ld];
            c = e.x;
            v = (idx < end) ? __int_as_float(e.y) : 0.f;
        }
        int n = min(64, end - base);
        for (int j = 0; j < n; j += 8) {
            float l[8], vv[8];
            #pragma unroll
            for (int t = 0; t < 8; ++t) {
                int cj = __shfl(c, j + t);
                vv[t] = __shfl(v, j + t);
                l[t] = fb[(size_t)cj * EMB + lane];   // 8 independent 256B gathers
            }
            #pragma unroll
            for (int t = 0; t < 8; ++t) sum += vv[t] * l[t];
        }
    }
    int o = wave * EMB + lane;
    if (!LAST) fn[o] = sum;
    if (FIRST) {
        float own = isUser ? uE[(size_t)wave * EMB + lane]
                           : iE[(size_t)(wave - U_NUMC) * EMB + lane];
        acc[o] = own + sum;
    } else {
        acc[o] += sum;
    }
}

// ---------------- batched dot of final embeddings ----------------
__global__ __launch_bounds__(256) void k_out(const float* __restrict__ acc,
                                             const int* __restrict__ userIdx,
                                             const int* __restrict__ itemIdx,
                                             float* __restrict__ out) {
    int wave = (blockIdx.x * blockDim.x + threadIdx.x) >> 6;
    int lane = threadIdx.x & 63;
    if (wave >= NBATCH) return;
    int u = userIdx[wave];
    int it = itemIdx[wave] + U_NUMC;
    float p = acc[u * EMB + lane] * acc[it * EMB + lane];
    #pragma unroll
    for (int offd = 32; offd; offd >>= 1) p += __shfl_xor(p, offd);
    if (lane == 0) out[wave] = p * (1.0f / 16.0f);   // (acc/4)·(acc/4)
}

extern "C" void kernel_launch(void* const* d_in, const int* in_sizes, int n_in,
                              void* d_out, int out_size, void* d_ws, size_t ws_size,
                              hipStream_t stream) {
    const float* uE      = (const float*)d_in[0];
    const float* iE      = (const float*)d_in[1];
    const int*   rows    = (const int*)d_in[2];    // [E], first half sorted by u
    const int*   cols    = (const int*)d_in[3];    // [E], first half = i + U_NUM
    const float* vals    = (const float*)d_in[4];  // [E], symmetric halves
    const int*   userIdx = (const int*)d_in[5];
    const int*   itemIdx = (const int*)d_in[6];
    const int E  = in_sizes[2];
    const int E1 = E / 2;

    char* ws = (char*)d_ws;
    size_t off = 0;
    auto alloc = [&](size_t bytes) -> void* {
        off = (off + 255) & ~(size_t)255;
        void* p = ws + off;
        off += bytes;
        return p;
    };
    float* f0      = (float*)alloc((size_t)NNODES * EMB * 4);
    float* f1      = (float*)alloc((size_t)NNODES * EMB * 4);
    float* acc     = (float*)alloc((size_t)NNODES * EMB * 4);
    int*   uptr    = (int*)alloc((size_t)(U_NUMC + 1) * 4);
    int*   iptr    = (int*)alloc((size_t)(I_NUMC + 1) * 4);
    int*   hist    = (int*)alloc((size_t)I_NUMC * 4);
    int*   cursor  = (int*)alloc((size_t)I_NUMC * 4);
    int*   bsum    = (int*)alloc((size_t)NB_I * 4);
    int*   boff    = (int*)alloc((size_t)NB_I * 4);
    int2*  item_uv = (int2*)alloc((size_t)E1 * 8);

    // zero histogram; build index structures (reused across all 3 layers)
    k_zero<<<(I_NUMC + 255) / 256, 256, 0, stream>>>(hist, I_NUMC);
    k_uptr<<<(U_NUMC + 256) / 256, 256, 0, stream>>>(rows, E1, uptr);
    k_hist<<<(E1 + 255) / 256, 256, 0, stream>>>(cols, E1, hist);
    k_scan1<<<NB_I, 256, 0, stream>>>(hist, bsum);
    k_scan2<<<1, 256, 0, stream>>>(bsum, boff, iptr);
    k_scan3<<<NB_I, 256, 0, stream>>>(hist, boff, iptr, cursor);
    k_scatter<<<(E1 + 255) / 256, 256, 0, stream>>>(rows, cols, vals, E1,
                                                    cursor, item_uv);

    // 3 propagation layers (layer 1 fused with init, layer 3 skips fn store)
    const int spmm_blocks = NNODES / 4;      // 4 waves (rows) per 256-thr block
    k_spmm<1, 0><<<spmm_blocks, 256, 0, stream>>>(uE, iE, nullptr, f1, acc,
                                                  uptr, cols, vals, iptr, item_uv);
    k_spmm<0, 0><<<spmm_blocks, 256, 0, stream>>>(uE, iE, f1, f0, acc,
                                                  uptr, cols, vals, iptr, item_uv);
    k_spmm<0, 1><<<spmm_blocks, 256, 0, stream>>>(uE, iE, f0, nullptr, acc,
                                                  uptr, cols, vals, iptr, item_uv);

    // final batched dot products
    k_out<<<NBATCH / 4, 256, 0, stream>>>(acc, userIdx, itemIdx, (float*)d_out);
}